// Round 19
// baseline (450.353 us; speedup 1.0000x reference)
//
#include <hip/hip_runtime.h>

// B=4, S=1024, EMB=1024, H=16, HD=64, MAXP=512
// Outputs (float32, concatenated): out0 [4,1024,1024], attn [64,1024,1024]

using s16x8 = __attribute__((ext_vector_type(8))) short;
using f32x4 = __attribute__((ext_vector_type(4))) float;

#define MFMA16 __builtin_amdgcn_mfma_f32_16x16x32_bf16

__device__ __forceinline__ float bf2f(unsigned short u) {
  union { unsigned int u; float f; } v; v.u = ((unsigned int)u) << 16; return v.f;
}
__device__ __forceinline__ unsigned short f2bf(float f) {
  union { float f; unsigned int u; } v; v.f = f;
  unsigned int r = (v.u + 0x7FFFu + ((v.u >> 16) & 1u)) >> 16;
  return (unsigned short)r;
}

// ---------- fused prep: 4x (1024x1024 transpose+cvt) + rel_k cvt + rel_v transpose ----------
__global__ __launch_bounds__(256)
void k_prep(const float* __restrict__ Wq, const float* __restrict__ Wk,
            const float* __restrict__ Wv, const float* __restrict__ Wo,
            unsigned short* __restrict__ wqt, unsigned short* __restrict__ wkt,
            unsigned short* __restrict__ wvt, unsigned short* __restrict__ wot,
            const float* __restrict__ rk, const float* __restrict__ rv,
            unsigned short* __restrict__ relkb, unsigned short* __restrict__ rvTb) {
  const int b = blockIdx.x;
  const int tid = threadIdx.x;
  if (b < 4096) {
    __shared__ float t[32][33];
    const int sel = b >> 10, idx = b & 1023;
    const float* W = sel == 0 ? Wq : (sel == 1 ? Wk : (sel == 2 ? Wv : Wo));
    unsigned short* Wt = sel == 0 ? wqt : (sel == 1 ? wkt : (sel == 2 ? wvt : wot));
    const int n0 = (idx & 31) * 32, k0 = (idx >> 5) * 32;
    const int tx = tid & 31, ty = tid >> 5;
#pragma unroll
    for (int r = 0; r < 4; ++r)
      t[ty * 4 + r][tx] = W[(size_t)(k0 + ty * 4 + r) * 1024 + n0 + tx];
    __syncthreads();
#pragma unroll
    for (int r = 0; r < 4; ++r)
      Wt[(size_t)(n0 + ty * 4 + r) * 1024 + k0 + tx] = f2bf(t[tx][ty * 4 + r]);
  } else {
    const int b2 = b - 4096;
    if (b2 < 33) {
      int i = (b2 * 256 + tid) * 8;
      if (i < 65600) {
        float4 a = *(const float4*)(rk + i);
        float4 c = *(const float4*)(rk + i + 4);
        s16x8 o;
        o[0] = (short)f2bf(a.x); o[1] = (short)f2bf(a.y); o[2] = (short)f2bf(a.z); o[3] = (short)f2bf(a.w);
        o[4] = (short)f2bf(c.x); o[5] = (short)f2bf(c.y); o[6] = (short)f2bf(c.z); o[7] = (short)f2bf(c.w);
        *(s16x8*)(relkb + i) = o;
      }
    } else {
      int i = (b2 - 33) * 256 + tid;
      if (i < 65600) {
        int p = i >> 6, d = i & 63;
        rvTb[d * 1040 + p] = f2bf(rv[i]);
      }
    }
  }
}

// ---------- fused QKV GEMM: f32 A reg-staged convert; Q/K per-head [bh][s][d]; V direct-transposed [bh][d][s] ----------
__global__ __launch_bounds__(256, 2)
void k_gemm_qkv(const float* __restrict__ Aq, const float* __restrict__ Ak, const float* __restrict__ Av,
                const unsigned short* __restrict__ Wq_, const unsigned short* __restrict__ Wk_,
                const unsigned short* __restrict__ Wv_,
                const float* __restrict__ bq_, const float* __restrict__ bk_, const float* __restrict__ bv_,
                unsigned short* __restrict__ Oq, unsigned short* __restrict__ Ok,
                unsigned short* __restrict__ Ov) {
  const int z = blockIdx.z;
  const float* A = z == 0 ? Aq : (z == 1 ? Ak : Av);
  const unsigned short* BT = z == 0 ? Wq_ : (z == 1 ? Wk_ : Wv_);
  const float* bias = z == 0 ? bq_ : (z == 1 ? bk_ : bv_);
  unsigned short* Cout = z == 0 ? Oq : (z == 1 ? Ok : Ov);

  __shared__ alignas(16) unsigned short aT[2][4096];
  __shared__ alignas(16) unsigned short bT[2][2048];
  const int tid = threadIdx.x;
  const int lane = tid & 63;
  const int l15 = lane & 15, lhi = lane >> 4;
  const int w = tid >> 6;
  const int wr = w * 32;
  const int brow = blockIdx.y * 128, bcol = blockIdx.x * 64;
  f32x4 acc[2][4] = {};

  const int c1 = tid, c2 = tid + 256;
  const int r1 = c1 >> 2, kA1 = (c1 & 3) * 8;
  const int r2 = c2 >> 2, kA2 = (c2 & 3) * 8;
  float4 a0, a1, a2, a3;
  s16x8 w1v, w2v;

#define LOADA(kt) do {                                                     \
    const float* p1 = A + (size_t)(brow + r1) * 1024 + (kt) * 32 + kA1;    \
    a0 = *(const float4*)p1; a1 = *(const float4*)(p1 + 4);                \
    const float* p2 = A + (size_t)(brow + r2) * 1024 + (kt) * 32 + kA2;    \
    a2 = *(const float4*)p2; a3 = *(const float4*)(p2 + 4);                \
  } while (0)
#define CVTA() do {                                                        \
    w1v[0] = (short)f2bf(a0.x); w1v[1] = (short)f2bf(a0.y);                \
    w1v[2] = (short)f2bf(a0.z); w1v[3] = (short)f2bf(a0.w);                \
    w1v[4] = (short)f2bf(a1.x); w1v[5] = (short)f2bf(a1.y);                \
    w1v[6] = (short)f2bf(a1.z); w1v[7] = (short)f2bf(a1.w);                \
    w2v[0] = (short)f2bf(a2.x); w2v[1] = (short)f2bf(a2.y);                \
    w2v[2] = (short)f2bf(a2.z); w2v[3] = (short)f2bf(a2.w);                \
    w2v[4] = (short)f2bf(a3.x); w2v[5] = (short)f2bf(a3.y);                \
    w2v[6] = (short)f2bf(a3.z); w2v[7] = (short)f2bf(a3.w);                \
  } while (0)
#define WRA(buf) do {                                                      \
    *(s16x8*)&aT[buf][c1 * 8] = w1v;                                       \
    *(s16x8*)&aT[buf][c2 * 8] = w2v;                                       \
  } while (0)
#define GLB(buf, kt) do {                                                  \
    int row = c1 >> 2, k8 = (c1 & 3) * 8;                                  \
    __builtin_amdgcn_global_load_lds(                                      \
      (const __attribute__((address_space(1))) void*)(BT + (size_t)(bcol + row) * 1024 + (kt) * 32 + k8), \
      (__attribute__((address_space(3))) void*)(&bT[buf][c1 * 8]), 16, 0, 0); \
  } while (0)

  LOADA(0); GLB(0, 0); CVTA(); WRA(0);
  int cur = 0;
  for (int kt = 0; kt < 32; ++kt) {
    __syncthreads();
    if (kt + 1 < 32) { LOADA(kt + 1); GLB(cur ^ 1, kt + 1); }
    s16x8 af[2], bfv[4];
#pragma unroll
    for (int m = 0; m < 2; ++m)
      af[m] = *(const s16x8*)&aT[cur][(wr + m * 16 + l15) * 32 + lhi * 8];
#pragma unroll
    for (int n = 0; n < 4; ++n)
      bfv[n] = *(const s16x8*)&bT[cur][(n * 16 + l15) * 32 + lhi * 8];
#pragma unroll
    for (int m = 0; m < 2; ++m)
#pragma unroll
      for (int n = 0; n < 4; ++n)
        acc[m][n] = MFMA16(af[m], bfv[n], acc[m][n], 0, 0, 0);
    if (kt + 1 < 32) { CVTA(); WRA(cur ^ 1); }
    __syncthreads();
    cur ^= 1;
  }
#undef LOADA
#undef CVTA
#undef WRA
#undef GLB

  if (z < 2) {
#pragma unroll
    for (int m = 0; m < 2; ++m) {
#pragma unroll
      for (int n = 0; n < 4; ++n) {
        int col = bcol + n * 16 + l15;
        float bs = bias[col];
#pragma unroll
        for (int j = 0; j < 4; ++j) {
          int r = brow + wr + m * 16 + lhi * 4 + j;
          float v = acc[m][n][j] + bs;
          int bb = r >> 10, s = r & 1023, h = col >> 6, d = col & 63;
          Cout[(((size_t)((bb << 4) + h) * 1024 + s) << 6) + d] = f2bf(v);
        }
      }
    }
  } else {
    // V: direct-transposed [bh][d][s]; j is s-consecutive -> packed 8-B stores
    const int h = bcol >> 6;
#pragma unroll
    for (int m = 0; m < 2; ++m) {
      int r0 = brow + wr + m * 16 + lhi * 4;
      int bb = r0 >> 10, s0 = r0 & 1023;
#pragma unroll
      for (int n = 0; n < 4; ++n) {
        int col = bcol + n * 16 + l15;
        int d = col & 63;
        float bs = bias[col];
        uint2 pk;
        pk.x = (unsigned int)f2bf(acc[m][n][0] + bs) | ((unsigned int)f2bf(acc[m][n][1] + bs) << 16);
        pk.y = (unsigned int)f2bf(acc[m][n][2] + bs) | ((unsigned int)f2bf(acc[m][n][3] + bs) << 16);
        *(uint2*)&Cout[(((size_t)((bb << 4) + h) << 16)) + (d << 10) + s0] = pk;
      }
    }
  }
}

// ---------- output GEMM: bf16 A (global_load_lds), f32 row-major out ----------
__global__ __launch_bounds__(256, 2)
void k_gemm_o(const unsigned short* __restrict__ A, const unsigned short* __restrict__ BT,
              const float* __restrict__ bias, float* __restrict__ Cout) {
  __shared__ alignas(16) unsigned short aT[2][4096];
  __shared__ alignas(16) unsigned short bT[2][2048];
  const int tid = threadIdx.x;
  const int lane = tid & 63;
  const int l15 = lane & 15, lhi = lane >> 4;
  const int w = tid >> 6;
  const int wr = w * 32;
  const int brow = blockIdx.y * 128, bcol = blockIdx.x * 64;
  f32x4 acc[2][4] = {};

#define STAGE(buf, kt) do {                                                              \
    int k0s = (kt) * 32;                                                                 \
    {                                                                                    \
      int c = tid;                                                                       \
      int row = c >> 2, k8 = (c & 3) * 8;                                                \
      __builtin_amdgcn_global_load_lds(                                                  \
        (const __attribute__((address_space(1))) void*)(A + (size_t)(brow + row) * 1024 + k0s + k8), \
        (__attribute__((address_space(3))) void*)(&aT[buf][c * 8]), 16, 0, 0);           \
      __builtin_amdgcn_global_load_lds(                                                  \
        (const __attribute__((address_space(1))) void*)(BT + (size_t)(bcol + row) * 1024 + k0s + k8),\
        (__attribute__((address_space(3))) void*)(&bT[buf][c * 8]), 16, 0, 0);           \
    }                                                                                    \
    {                                                                                    \
      int c = tid + 256;                                                                 \
      int row = c >> 2, k8 = (c & 3) * 8;                                                \
      __builtin_amdgcn_global_load_lds(                                                  \
        (const __attribute__((address_space(1))) void*)(A + (size_t)(brow + row) * 1024 + k0s + k8), \
        (__attribute__((address_space(3))) void*)(&aT[buf][c * 8]), 16, 0, 0);           \
    }                                                                                    \
  } while (0)

  int cur = 0;
  STAGE(0, 0);
  for (int kt = 0; kt < 32; ++kt) {
    __syncthreads();
    if (kt + 1 < 32) STAGE(cur ^ 1, kt + 1);
    s16x8 af[2], bfv[4];
#pragma unroll
    for (int m = 0; m < 2; ++m)
      af[m] = *(const s16x8*)&aT[cur][(wr + m * 16 + l15) * 32 + lhi * 8];
#pragma unroll
    for (int n = 0; n < 4; ++n)
      bfv[n] = *(const s16x8*)&bT[cur][(n * 16 + l15) * 32 + lhi * 8];
#pragma unroll
    for (int m = 0; m < 2; ++m)
#pragma unroll
      for (int n = 0; n < 4; ++n)
        acc[m][n] = MFMA16(af[m], bfv[n], acc[m][n], 0, 0, 0);
    __syncthreads();
    cur ^= 1;
  }
#undef STAGE

#pragma unroll
  for (int m = 0; m < 2; ++m) {
#pragma unroll
    for (int n = 0; n < 4; ++n) {
      int col = bcol + n * 16 + l15;
      float bs = bias[col];
#pragma unroll
      for (int j = 0; j < 4; ++j) {
        int r = brow + wr + m * 16 + lhi * 4 + j;
        Cout[(size_t)r * 1024 + col] = acc[m][n][j] + bs;
      }
    }
  }
}

// ---------- fused attention: 38KB LDS (4 blocks/CU), windowed Tb + in-register funnel rel_v ----------
#define RPW 1032   // pbuf row stride (elems)
#define TBW 136    // windowed Tb row stride (elems); 272B

__global__ __launch_bounds__(256, 4)
void k_attn(const unsigned short* __restrict__ qb, const unsigned short* __restrict__ kbm,
            const unsigned short* __restrict__ vT, const unsigned short* __restrict__ relk,
            const unsigned short* __restrict__ rvT, float* __restrict__ attn_out,
            unsigned short* __restrict__ xscr) {
  __shared__ alignas(16) unsigned short pbuf[16 * RPW];  // 33,024 B unnormalized exp
  __shared__ alignas(16) unsigned short Tb[16 * TBW];    //  4,352 B windowed rel-table
  __shared__ float red[4][16];
  __shared__ float izS[16], plS[16], phS[16];

  const int tid = threadIdx.x;
  const int lane = tid & 63;
  const int w = tid >> 6;                       // 0..3
  const int l15 = lane & 15, lhi = lane >> 4;
  const int orig = ((blockIdx.x & 7) << 9) | (blockIdx.x >> 3);
  const int bh = orig >> 6;
  const int q0 = (orig & 63) << 4;

  const unsigned short* Qh = qb + ((size_t)bh << 16);
  const unsigned short* Kh = kbm + ((size_t)bh << 16);
  const unsigned short* Vth = vT + ((size_t)bh << 16);

  const unsigned short* qp = Qh + (size_t)(q0 + l15) * 64 + lhi * 8;
  s16x8 qa0 = *(const s16x8*)qp;
  s16x8 qa1 = *(const s16x8*)(qp + 32);

  // ---- pass 1: 8 windows of 128 k; per-window Tb sweep + 2-iter hot loop ----
  float zp = 0.f;
#pragma unroll 1
  for (int win = 0; win < 8; ++win) {
    const int kw = win << 7;
    __syncthreads();   // prior window's Tb reads done

    // clamped MFMA sweep: Tb[qi][u] = Q[qi].relk[clamp(p)], u = p - kw + q0 + qi - 512
    {
      const int PT0 = ((kw - q0 + 497) >> 4) << 4;
      const int PT1 = kw - q0 + 639;
      for (int pt = PT0 + w * 16; pt <= PT1; pt += 64) {
        int pr = pt + l15; pr = pr < 0 ? 0 : (pr > 1024 ? 1024 : pr);
        const unsigned short* rp = relk + (size_t)pr * 64 + lhi * 8;
        s16x8 rf0 = *(const s16x8*)rp;
        s16x8 rf1 = *(const s16x8*)(rp + 32);
        f32x4 d = {0.f, 0.f, 0.f, 0.f};
        d = MFMA16(qa0, rf0, d, 0, 0, 0);
        d = MFMA16(qa1, rf1, d, 0, 0, 0);
#pragma unroll
        for (int j = 0; j < 4; ++j) {
          int qi = lhi * 4 + j;
          int u = pt + l15 - kw + q0 + qi - 512;
          if (u >= 0 && u < 128) Tb[qi * TBW + u] = f2bf(d[j]);
        }
      }
    }
    __syncthreads();   // Tb window ready

    // hot loop: 2 iterations, both K-load pairs issued upfront
    const unsigned short* kbp = Kh + (size_t)(kw + w * 16 + l15) * 64 + lhi * 8;
    s16x8 kf0a = *(const s16x8*)kbp;
    s16x8 kf1a = *(const s16x8*)(kbp + 32);
    s16x8 kf0b = *(const s16x8*)(kbp + 4096);
    s16x8 kf1b = *(const s16x8*)(kbp + 4096 + 32);
#pragma unroll
    for (int n = 0; n < 2; ++n) {
      const int ktile = kw + w * 16 + n * 64;
      s16x8 kf0 = n ? kf0b : kf0a;
      s16x8 kf1 = n ? kf1b : kf1a;
      f32x4 c = {0.f, 0.f, 0.f, 0.f};
      __builtin_amdgcn_s_setprio(1);
      c = MFMA16(kf0, qa0, c, 0, 0, 0);
      c = MFMA16(kf1, qa1, c, 0, 0, 0);
      __builtin_amdgcn_s_setprio(0);
      uint2 tv = *(const uint2*)&Tb[l15 * TBW + (ktile - kw) + lhi * 4];
      float t0 = bf2f((unsigned short)(tv.x & 0xFFFF));
      float t1 = bf2f((unsigned short)(tv.x >> 16));
      float t2 = bf2f((unsigned short)(tv.y & 0xFFFF));
      float t3 = bf2f((unsigned short)(tv.y >> 16));
      float e0 = __expf((c[0] + t0) * 0.125f);
      float e1 = __expf((c[1] + t1) * 0.125f);
      float e2 = __expf((c[2] + t2) * 0.125f);
      float e3 = __expf((c[3] + t3) * 0.125f);
      zp += (e0 + e1) + (e2 + e3);
      uint2 pk;
      pk.x = (unsigned int)f2bf(e0) | ((unsigned int)f2bf(e1) << 16);
      pk.y = (unsigned int)f2bf(e2) | ((unsigned int)f2bf(e3) << 16);
      *(uint2*)&pbuf[l15 * RPW + ktile + lhi * 4] = pk;
    }
  }

  // ---- Z reduction ----
  zp += __shfl_xor(zp, 16, 64);
  zp += __shfl_xor(zp, 32, 64);
  if (lane < 16) red[w][lane] = zp;
  __syncthreads();   // B1: pbuf + red complete
  if (tid < 16)
    izS[tid] = 1.0f / (red[0][tid] + red[1][tid] + red[2][tid] + red[3][tid]);

  // ---- clip-mass (wave-local rows 4w..4w+3) ----
  {
    const int qi = tid >> 4, tq = tid & 15;
    const int qa = q0 + qi;
    int lo, hi;
    const bool isPh = (qa < 512);
    if (isPh) { lo = qa + 512; hi = 1024; }
    else      { lo = 0;        hi = qa - 511; }
    float s = 0.f;
    const unsigned short* srow = pbuf + qi * RPW;
    const int kb0 = lo & ~7;
    for (int k8 = kb0 + tq * 8; k8 < hi; k8 += 128) {
      s16x8 v8 = *(const s16x8*)&srow[k8];
#pragma unroll
      for (int e = 0; e < 8; ++e) {
        int k = k8 + e;
        s += (k >= lo && k < hi) ? bf2f((unsigned short)v8[e]) : 0.f;
      }
    }
#pragma unroll
    for (int off = 1; off < 16; off <<= 1) s += __shfl_xor(s, off, 64);
    if (tq == 0) { plS[qi] = isPh ? 0.f : s; phS[qi] = isPh ? s : 0.f; }
  }
  __syncthreads();   // B2: izS, plS, phS visible block-wide

  // ---- PV: wave w -> d-group w, full k (p from LDS, V^T from global/L2) ----
  f32x4 acc = {0.f, 0.f, 0.f, 0.f};
  const int d0w = w << 4;
  const unsigned short* vrow = Vth + (size_t)(d0w + l15) * 1024 + lhi * 8;
#pragma unroll 8
  for (int kc = 0; kc < 1024; kc += 32) {
    s16x8 pa = *(const s16x8*)&pbuf[l15 * RPW + kc + lhi * 8];
    s16x8 vf = *(const s16x8*)(vrow + kc);
    acc = MFMA16(pa, vf, acc, 0, 0, 0);
  }

  // ---- normalized attn -> d_out (f32, contiguous NT stores) ----
  {
    float* ao = attn_out + ((size_t)bh << 20) + ((size_t)q0 << 10);
#pragma unroll
    for (int n = 0; n < 8; ++n) {
      int row = (tid >> 7) + n * 2;
      int c8 = (tid & 127) << 3;
      float iz = izS[row];
      s16x8 p8 = *(const s16x8*)&pbuf[row * RPW + c8];
      f32x4 o0, o1;
      o0[0] = bf2f((unsigned short)p8[0]) * iz; o0[1] = bf2f((unsigned short)p8[1]) * iz;
      o0[2] = bf2f((unsigned short)p8[2]) * iz; o0[3] = bf2f((unsigned short)p8[3]) * iz;
      o1[0] = bf2f((unsigned short)p8[4]) * iz; o1[1] = bf2f((unsigned short)p8[5]) * iz;
      o1[2] = bf2f((unsigned short)p8[6]) * iz; o1[3] = bf2f((unsigned short)p8[7]) * iz;
      __builtin_nontemporal_store(o0, (f32x4*)(ao + (row << 10) + c8));
      __builtin_nontemporal_store(o1, (f32x4*)(ao + (row << 10) + c8 + 4));
    }
  }

  // ---- rel_v: W[q][u] = p[q][q0+q+u-512] via in-register funnel shift (r16-validated) ----
  const unsigned short* rrow = rvT + (size_t)(d0w + l15) * 1040 + lhi * 8;
  const float pl = plS[l15];
  const int ssh = l15 & 7, shs = ssh >> 1;
  const bool sodd = (ssh & 1) != 0;
  const unsigned short* srow = pbuf + l15 * RPW;
  for (int uc = 0; uc < 1024; uc += 32) {
    if (uc + 79 + q0 <= 512) continue;        // all lanes k+8 <= 0 -> zero fragment
    if (uc + q0 >= 1536) break;               // all lanes k >= 1024
    const int base = q0 + l15 + uc + lhi * 8 - 512;
    s16x8 wa;
    if (base >= 8 && base <= 1008) {
      const int A = base - ssh;
      union { s16x8 v; unsigned int u[4]; } a0u, a1u, ov;
      a0u.v = *(const s16x8*)&srow[A];
      a1u.v = *(const s16x8*)&srow[A + 8];
      unsigned int wd[8];
#pragma unroll
      for (int j2 = 0; j2 < 4; ++j2) { wd[j2] = a0u.u[j2]; wd[4 + j2] = a1u.u[j2]; }
      unsigned int v7[7];
#pragma unroll
      for (int j2 = 0; j2 < 7; ++j2) {
        unsigned int sf = (wd[j2] >> 16) | (wd[j2 + 1] << 16);
        v7[j2] = sodd ? sf : wd[j2];
      }
#pragma unroll
      for (int j2 = 0; j2 < 4; ++j2) {
        unsigned int t0 = (shs & 1) ? v7[j2 + 1] : v7[j2];
        unsigned int t1 = (shs & 1) ? v7[j2 + 3] : v7[j2 + 2];
        ov.u[j2] = (shs & 2) ? t1 : t0;
      }
      wa = ov.v;
    } else if (base + 8 <= 0 || base >= 1024) {
      wa = (s16x8){0, 0, 0, 0, 0, 0, 0, 0};
    } else {
#pragma unroll
      for (int e = 0; e < 8; ++e) {
        int k = base + e;
        int kc2 = k < 0 ? 0 : (k > 1023 ? 1023 : k);
        unsigned short vv = srow[kc2];
        wa[e] = (k >= 0 && k < 1024) ? (short)vv : (short)0;
      }
    }
    if (uc == 0 && lhi == 0) wa[0] = (short)f2bf(pl);   // u=0 slot carries clip-low mass
    s16x8 rb = *(const s16x8*)(rrow + uc);
    acc = MFMA16(wa, rb, acc, 0, 0, 0);
  }

  // ---- epilogue: + phigh * rel_v[1024], scale by iz, scrambled bf16 store ----
  float rv1024 = bf2f(rvT[(size_t)(d0w + l15) * 1040 + 1024]);
  const size_t fb = ((size_t)(bh >> 2) << 18) + ((size_t)(bh & 3) << 6);
#pragma unroll
  for (int j = 0; j < 4; ++j) {
    int qi = lhi * 4 + j;
    float v = (acc[j] + phS[qi] * rv1024) * izS[qi];
    xscr[fb + ((size_t)(q0 + qi) << 8) + d0w + l15] = f2bf(v);
  }
}

extern "C" void kernel_launch(void* const* d_in, const int* in_sizes, int n_in,
                              void* d_out, int out_size, void* d_ws, size_t ws_size,
                              hipStream_t stream) {
  (void)in_sizes; (void)n_in; (void)out_size; (void)ws_size;
  const float* query = (const float*)d_in[0];
  const float* key   = (const float*)d_in[1];
  const float* value = (const float*)d_in[2];
  const float* Wq = (const float*)d_in[3];
  const float* bq = (const float*)d_in[4];
  const float* Wk = (const float*)d_in[5];
  const float* bk = (const float*)d_in[6];
  const float* Wv = (const float*)d_in[7];
  const float* bv = (const float*)d_in[8];
  const float* Wo = (const float*)d_in[9];
  const float* bo = (const float*)d_in[10];
  const float* rel_k = (const float*)d_in[11];
  const float* rel_v = (const float*)d_in[12];

  char* ws = (char*)d_ws;
  const size_t MB = 1024 * 1024;
  unsigned short* qb    = (unsigned short*)(ws);            //  0-8 MB
  unsigned short* kbuf  = (unsigned short*)(ws + 8 * MB);   //  8-16
  unsigned short* xscr  = (unsigned short*)(ws + 16 * MB);  // 16-24
  unsigned short* vTb   = (unsigned short*)(ws + 24 * MB);  // 24-32 (V written transposed)
  unsigned short* wqt   = (unsigned short*)(ws + 32 * MB);  // 32-34
  unsigned short* wkt   = (unsigned short*)(ws + 34 * MB);  // 34-36
  unsigned short* wvt   = (unsigned short*)(ws + 36 * MB);  // 36-38
  unsigned short* wot   = (unsigned short*)(ws + 38 * MB);  // 38-40
  unsigned short* relkb = (unsigned short*)(ws + 40 * MB);              // ~0.13 MB
  unsigned short* rvTb  = (unsigned short*)(ws + 40 * MB + 256 * 1024); // ~0.13 MB

  float* out0 = (float*)d_out;
  float* attn_out = out0 + 4194304;

  k_prep<<<4386, 256, 0, stream>>>(Wq, Wk, Wv, Wo, wqt, wkt, wvt, wot,
                                   rel_k, rel_v, relkb, rvTb);

  k_gemm_qkv<<<dim3(16, 32, 3), 256, 0, stream>>>(query, key, value,
                                                  wqt, wkt, wvt,
                                                  bq, bk, bv,
                                                  qb, kbuf, vTb);

  k_attn<<<4096, 256, 0, stream>>>(qb, kbuf, vTb, relkb, rvTb, attn_out, xscr);

  k_gemm_o<<<dim3(16, 32), 256, 0, stream>>>(xscr, wot, bo, out0);
}

// Round 20
// 332.189 us; speedup vs baseline: 1.3557x; 1.3557x over previous
//
#include <hip/hip_runtime.h>

// B=4, S=1024, EMB=1024, H=16, HD=64, MAXP=512
// Outputs (float32, concatenated): out0 [4,1024,1024], attn [64,1024,1024]
// FINAL: r18 champion configuration (332.2 us measured).

using s16x8 = __attribute__((ext_vector_type(8))) short;
using f32x4 = __attribute__((ext_vector_type(4))) float;

#define MFMA16 __builtin_amdgcn_mfma_f32_16x16x32_bf16

__device__ __forceinline__ float bf2f(unsigned short u) {
  union { unsigned int u; float f; } v; v.u = ((unsigned int)u) << 16; return v.f;
}
__device__ __forceinline__ unsigned short f2bf(float f) {
  union { float f; unsigned int u; } v; v.f = f;
  unsigned int r = (v.u + 0x7FFFu + ((v.u >> 16) & 1u)) >> 16;
  return (unsigned short)r;
}

// ---------- fused prep: 4x (1024x1024 transpose+cvt) + rel_k cvt + rel_v transpose ----------
__global__ __launch_bounds__(256)
void k_prep(const float* __restrict__ Wq, const float* __restrict__ Wk,
            const float* __restrict__ Wv, const float* __restrict__ Wo,
            unsigned short* __restrict__ wqt, unsigned short* __restrict__ wkt,
            unsigned short* __restrict__ wvt, unsigned short* __restrict__ wot,
            const float* __restrict__ rk, const float* __restrict__ rv,
            unsigned short* __restrict__ relkb, unsigned short* __restrict__ rvTb) {
  const int b = blockIdx.x;
  const int tid = threadIdx.x;
  if (b < 4096) {
    __shared__ float t[32][33];
    const int sel = b >> 10, idx = b & 1023;
    const float* W = sel == 0 ? Wq : (sel == 1 ? Wk : (sel == 2 ? Wv : Wo));
    unsigned short* Wt = sel == 0 ? wqt : (sel == 1 ? wkt : (sel == 2 ? wvt : wot));
    const int n0 = (idx & 31) * 32, k0 = (idx >> 5) * 32;
    const int tx = tid & 31, ty = tid >> 5;
#pragma unroll
    for (int r = 0; r < 4; ++r)
      t[ty * 4 + r][tx] = W[(size_t)(k0 + ty * 4 + r) * 1024 + n0 + tx];
    __syncthreads();
#pragma unroll
    for (int r = 0; r < 4; ++r)
      Wt[(size_t)(n0 + ty * 4 + r) * 1024 + k0 + tx] = f2bf(t[tx][ty * 4 + r]);
  } else {
    const int b2 = b - 4096;
    if (b2 < 33) {
      int i = (b2 * 256 + tid) * 8;
      if (i < 65600) {
        float4 a = *(const float4*)(rk + i);
        float4 c = *(const float4*)(rk + i + 4);
        s16x8 o;
        o[0] = (short)f2bf(a.x); o[1] = (short)f2bf(a.y); o[2] = (short)f2bf(a.z); o[3] = (short)f2bf(a.w);
        o[4] = (short)f2bf(c.x); o[5] = (short)f2bf(c.y); o[6] = (short)f2bf(c.z); o[7] = (short)f2bf(c.w);
        *(s16x8*)(relkb + i) = o;
      }
    } else {
      int i = (b2 - 33) * 256 + tid;
      if (i < 65600) {
        int p = i >> 6, d = i & 63;
        rvTb[d * 1040 + p] = f2bf(rv[i]);
      }
    }
  }
}

// ---------- fused QKV GEMM: f32 A reg-staged convert; Q/K per-head [bh][s][d]; V direct-transposed [bh][d][s] ----------
__global__ __launch_bounds__(256, 2)
void k_gemm_qkv(const float* __restrict__ Aq, const float* __restrict__ Ak, const float* __restrict__ Av,
                const unsigned short* __restrict__ Wq_, const unsigned short* __restrict__ Wk_,
                const unsigned short* __restrict__ Wv_,
                const float* __restrict__ bq_, const float* __restrict__ bk_, const float* __restrict__ bv_,
                unsigned short* __restrict__ Oq, unsigned short* __restrict__ Ok,
                unsigned short* __restrict__ Ov) {
  const int z = blockIdx.z;
  const float* A = z == 0 ? Aq : (z == 1 ? Ak : Av);
  const unsigned short* BT = z == 0 ? Wq_ : (z == 1 ? Wk_ : Wv_);
  const float* bias = z == 0 ? bq_ : (z == 1 ? bk_ : bv_);
  unsigned short* Cout = z == 0 ? Oq : (z == 1 ? Ok : Ov);

  __shared__ alignas(16) unsigned short aT[2][4096];
  __shared__ alignas(16) unsigned short bT[2][2048];
  const int tid = threadIdx.x;
  const int lane = tid & 63;
  const int l15 = lane & 15, lhi = lane >> 4;
  const int w = tid >> 6;
  const int wr = w * 32;
  const int brow = blockIdx.y * 128, bcol = blockIdx.x * 64;
  f32x4 acc[2][4] = {};

  const int c1 = tid, c2 = tid + 256;
  const int r1 = c1 >> 2, kA1 = (c1 & 3) * 8;
  const int r2 = c2 >> 2, kA2 = (c2 & 3) * 8;
  float4 a0, a1, a2, a3;
  s16x8 w1v, w2v;

#define LOADA(kt) do {                                                     \
    const float* p1 = A + (size_t)(brow + r1) * 1024 + (kt) * 32 + kA1;    \
    a0 = *(const float4*)p1; a1 = *(const float4*)(p1 + 4);                \
    const float* p2 = A + (size_t)(brow + r2) * 1024 + (kt) * 32 + kA2;    \
    a2 = *(const float4*)p2; a3 = *(const float4*)(p2 + 4);                \
  } while (0)
#define CVTA() do {                                                        \
    w1v[0] = (short)f2bf(a0.x); w1v[1] = (short)f2bf(a0.y);                \
    w1v[2] = (short)f2bf(a0.z); w1v[3] = (short)f2bf(a0.w);                \
    w1v[4] = (short)f2bf(a1.x); w1v[5] = (short)f2bf(a1.y);                \
    w1v[6] = (short)f2bf(a1.z); w1v[7] = (short)f2bf(a1.w);                \
    w2v[0] = (short)f2bf(a2.x); w2v[1] = (short)f2bf(a2.y);                \
    w2v[2] = (short)f2bf(a2.z); w2v[3] = (short)f2bf(a2.w);                \
    w2v[4] = (short)f2bf(a3.x); w2v[5] = (short)f2bf(a3.y);                \
    w2v[6] = (short)f2bf(a3.z); w2v[7] = (short)f2bf(a3.w);                \
  } while (0)
#define WRA(buf) do {                                                      \
    *(s16x8*)&aT[buf][c1 * 8] = w1v;                                       \
    *(s16x8*)&aT[buf][c2 * 8] = w2v;                                       \
  } while (0)
#define GLB(buf, kt) do {                                                  \
    int row = c1 >> 2, k8 = (c1 & 3) * 8;                                  \
    __builtin_amdgcn_global_load_lds(                                      \
      (const __attribute__((address_space(1))) void*)(BT + (size_t)(bcol + row) * 1024 + (kt) * 32 + k8), \
      (__attribute__((address_space(3))) void*)(&bT[buf][c1 * 8]), 16, 0, 0); \
  } while (0)

  LOADA(0); GLB(0, 0); CVTA(); WRA(0);
  int cur = 0;
  for (int kt = 0; kt < 32; ++kt) {
    __syncthreads();
    if (kt + 1 < 32) { LOADA(kt + 1); GLB(cur ^ 1, kt + 1); }
    s16x8 af[2], bfv[4];
#pragma unroll
    for (int m = 0; m < 2; ++m)
      af[m] = *(const s16x8*)&aT[cur][(wr + m * 16 + l15) * 32 + lhi * 8];
#pragma unroll
    for (int n = 0; n < 4; ++n)
      bfv[n] = *(const s16x8*)&bT[cur][(n * 16 + l15) * 32 + lhi * 8];
#pragma unroll
    for (int m = 0; m < 2; ++m)
#pragma unroll
      for (int n = 0; n < 4; ++n)
        acc[m][n] = MFMA16(af[m], bfv[n], acc[m][n], 0, 0, 0);
    if (kt + 1 < 32) { CVTA(); WRA(cur ^ 1); }
    __syncthreads();
    cur ^= 1;
  }
#undef LOADA
#undef CVTA
#undef WRA
#undef GLB

  if (z < 2) {
    // Q/K: per-head [bh][s][d], scalar stores
#pragma unroll
    for (int m = 0; m < 2; ++m) {
#pragma unroll
      for (int n = 0; n < 4; ++n) {
        int col = bcol + n * 16 + l15;
        float bs = bias[col];
#pragma unroll
        for (int j = 0; j < 4; ++j) {
          int r = brow + wr + m * 16 + lhi * 4 + j;
          float v = acc[m][n][j] + bs;
          int bb = r >> 10, s = r & 1023, h = col >> 6, d = col & 63;
          Cout[(((size_t)((bb << 4) + h) * 1024 + s) << 6) + d] = f2bf(v);
        }
      }
    }
  } else {
    // V: direct-transposed [bh][d][s]; j is s-consecutive -> packed 8-B stores
    const int h = bcol >> 6;   // 64-wide head-aligned tile
#pragma unroll
    for (int m = 0; m < 2; ++m) {
      int r0 = brow + wr + m * 16 + lhi * 4;
      int bb = r0 >> 10, s0 = r0 & 1023;
#pragma unroll
      for (int n = 0; n < 4; ++n) {
        int col = bcol + n * 16 + l15;
        int d = col & 63;
        float bs = bias[col];
        uint2 pk;
        pk.x = (unsigned int)f2bf(acc[m][n][0] + bs) | ((unsigned int)f2bf(acc[m][n][1] + bs) << 16);
        pk.y = (unsigned int)f2bf(acc[m][n][2] + bs) | ((unsigned int)f2bf(acc[m][n][3] + bs) << 16);
        *(uint2*)&Cout[(((size_t)((bb << 4) + h) << 16)) + (d << 10) + s0] = pk;
      }
    }
  }
}

// ---------- output GEMM: bf16 A (global_load_lds), f32 row-major out ----------
__global__ __launch_bounds__(256, 2)
void k_gemm_o(const unsigned short* __restrict__ A, const unsigned short* __restrict__ BT,
              const float* __restrict__ bias, float* __restrict__ Cout) {
  __shared__ alignas(16) unsigned short aT[2][4096];
  __shared__ alignas(16) unsigned short bT[2][2048];
  const int tid = threadIdx.x;
  const int lane = tid & 63;
  const int l15 = lane & 15, lhi = lane >> 4;
  const int w = tid >> 6;
  const int wr = w * 32;
  const int brow = blockIdx.y * 128, bcol = blockIdx.x * 64;
  f32x4 acc[2][4] = {};

#define STAGE(buf, kt) do {                                                              \
    int k0s = (kt) * 32;                                                                 \
    {                                                                                    \
      int c = tid;                                                                       \
      int row = c >> 2, k8 = (c & 3) * 8;                                                \
      __builtin_amdgcn_global_load_lds(                                                  \
        (const __attribute__((address_space(1))) void*)(A + (size_t)(brow + row) * 1024 + k0s + k8), \
        (__attribute__((address_space(3))) void*)(&aT[buf][c * 8]), 16, 0, 0);           \
      __builtin_amdgcn_global_load_lds(                                                  \
        (const __attribute__((address_space(1))) void*)(BT + (size_t)(bcol + row) * 1024 + k0s + k8),\
        (__attribute__((address_space(3))) void*)(&bT[buf][c * 8]), 16, 0, 0);           \
    }                                                                                    \
    {                                                                                    \
      int c = tid + 256;                                                                 \
      int row = c >> 2, k8 = (c & 3) * 8;                                                \
      __builtin_amdgcn_global_load_lds(                                                  \
        (const __attribute__((address_space(1))) void*)(A + (size_t)(brow + row) * 1024 + k0s + k8), \
        (__attribute__((address_space(3))) void*)(&aT[buf][c * 8]), 16, 0, 0);           \
    }                                                                                    \
  } while (0)

  int cur = 0;
  STAGE(0, 0);
  for (int kt = 0; kt < 32; ++kt) {
    __syncthreads();
    if (kt + 1 < 32) STAGE(cur ^ 1, kt + 1);
    s16x8 af[2], bfv[4];
#pragma unroll
    for (int m = 0; m < 2; ++m)
      af[m] = *(const s16x8*)&aT[cur][(wr + m * 16 + l15) * 32 + lhi * 8];
#pragma unroll
    for (int n = 0; n < 4; ++n)
      bfv[n] = *(const s16x8*)&bT[cur][(n * 16 + l15) * 32 + lhi * 8];
#pragma unroll
    for (int m = 0; m < 2; ++m)
#pragma unroll
      for (int n = 0; n < 4; ++n)
        acc[m][n] = MFMA16(af[m], bfv[n], acc[m][n], 0, 0, 0);
    __syncthreads();
    cur ^= 1;
  }
#undef STAGE

#pragma unroll
  for (int m = 0; m < 2; ++m) {
#pragma unroll
    for (int n = 0; n < 4; ++n) {
      int col = bcol + n * 16 + l15;
      float bs = bias[col];
#pragma unroll
      for (int j = 0; j < 4; ++j) {
        int r = brow + wr + m * 16 + lhi * 4 + j;
        Cout[(size_t)r * 1024 + col] = acc[m][n][j] + bs;
      }
    }
  }
}

// ---------- fused attention monolith (champion r12 schedule, 264 us floor) ----------
#define RPW 1032   // pbuf row stride (elems)
#define PWP 520    // Tb / pw row stride (elems)

__global__ __launch_bounds__(256, 3)
void k_attn(const unsigned short* __restrict__ qb, const unsigned short* __restrict__ kbm,
            const unsigned short* __restrict__ vT, const unsigned short* __restrict__ relk,
            const unsigned short* __restrict__ rvT, float* __restrict__ attn_out,
            unsigned short* __restrict__ xscr) {
  __shared__ alignas(16) unsigned short pbuf[16 * RPW];   // 33,024 B unnormalized exp
  __shared__ alignas(16) unsigned short TbPw[16 * PWP];   // 16,640 B rel-table / pw
  __shared__ float red[4][16];
  __shared__ float izS[16], plS[16], phS[16];

  const int tid = threadIdx.x;
  const int lane = tid & 63;
  const int w = tid >> 6;                       // 0..3
  const int l15 = lane & 15, lhi = lane >> 4;
  const int orig = ((blockIdx.x & 7) << 9) | (blockIdx.x >> 3);
  const int bh = orig >> 6;
  const int q0 = (orig & 63) << 4;

  const unsigned short* Qh = qb + ((size_t)bh << 16);
  const unsigned short* Kh = kbm + ((size_t)bh << 16);
  const unsigned short* Vth = vT + ((size_t)bh << 16);

  const unsigned short* qp = Qh + (size_t)(q0 + l15) * 64 + lhi * 8;
  s16x8 qa0 = *(const s16x8*)qp;
  s16x8 qa1 = *(const s16x8*)(qp + 32);

  // ---- pass 1 (two 512-k halves): clamped-sweep Tb, then batched hot loop ----
  float zp = 0.f;
  for (int half = 0; half < 2; ++half) {
    const int khalf = half << 9;
    __syncthreads();   // prior readers of TbPw done

    {
      const int PT0 = ((khalf - q0 + 497) >> 4) << 4;
      const int PT1 = khalf - q0 + 1023;
      for (int pt = PT0 + w * 16; pt <= PT1; pt += 64) {
        int pr = pt + l15; pr = pr < 0 ? 0 : (pr > 1024 ? 1024 : pr);
        const unsigned short* rp = relk + (size_t)pr * 64 + lhi * 8;
        s16x8 rf0 = *(const s16x8*)rp;
        s16x8 rf1 = *(const s16x8*)(rp + 32);
        f32x4 d = {0.f, 0.f, 0.f, 0.f};
        d = MFMA16(qa0, rf0, d, 0, 0, 0);
        d = MFMA16(qa1, rf1, d, 0, 0, 0);
#pragma unroll
        for (int j = 0; j < 4; ++j) {
          int qi = lhi * 4 + j;
          int u = pt + l15 - khalf + q0 + qi - 512;
          if (u >= 0 && u < 512) TbPw[qi * PWP + u] = f2bf(d[j]);
        }
      }
    }
    __syncthreads();

    // hot loop: 2 batches of 4 independent iterations (8 K-loads in flight)
    const unsigned short* kbp = Kh + (size_t)(khalf + w * 16 + l15) * 64 + lhi * 8;
#pragma unroll
    for (int g = 0; g < 2; ++g) {
      s16x8 kf0[4], kf1[4];
#pragma unroll
      for (int n = 0; n < 4; ++n) {
        const unsigned short* p = kbp + (size_t)(g * 4 + n) * 4096;
        kf0[n] = *(const s16x8*)p;
        kf1[n] = *(const s16x8*)(p + 32);
      }
#pragma unroll
      for (int n = 0; n < 4; ++n) {
        const int ktile = khalf + w * 16 + (g * 4 + n) * 64;
        f32x4 c = {0.f, 0.f, 0.f, 0.f};
        __builtin_amdgcn_s_setprio(1);
        c = MFMA16(kf0[n], qa0, c, 0, 0, 0);
        c = MFMA16(kf1[n], qa1, c, 0, 0, 0);
        __builtin_amdgcn_s_setprio(0);
        uint2 tv = *(const uint2*)&TbPw[l15 * PWP + (ktile - khalf) + lhi * 4];
        float t0 = bf2f((unsigned short)(tv.x & 0xFFFF));
        float t1 = bf2f((unsigned short)(tv.x >> 16));
        float t2 = bf2f((unsigned short)(tv.y & 0xFFFF));
        float t3 = bf2f((unsigned short)(tv.y >> 16));
        float e0 = __expf((c[0] + t0) * 0.125f);
        float e1 = __expf((c[1] + t1) * 0.125f);
        float e2 = __expf((c[2] + t2) * 0.125f);
        float e3 = __expf((c[3] + t3) * 0.125f);
        zp += (e0 + e1) + (e2 + e3);
        uint2 pk;
        pk.x = (unsigned int)f2bf(e0) | ((unsigned int)f2bf(e1) << 16);
        pk.y = (unsigned int)f2bf(e2) | ((unsigned int)f2bf(e3) << 16);
        *(uint2*)&pbuf[l15 * RPW + ktile + lhi * 4] = pk;
      }
    }
  }

  // ---- Z reduction ----
  zp += __shfl_xor(zp, 16, 64);
  zp += __shfl_xor(zp, 32, 64);
  if (lane < 16) red[w][lane] = zp;
  __syncthreads();   // B1: pbuf + red complete (TbPw readers also done)
  if (tid < 16)
    izS[tid] = 1.0f / (red[0][tid] + red[1][tid] + red[2][tid] + red[3][tid]);

  // ---- clip-mass (wave-local: wave w owns rows 4w..4w+3) ----
  {
    const int qi = tid >> 4, tq = tid & 15;
    const int qa = q0 + qi;
    int lo, hi;
    const bool isPh = (qa < 512);
    if (isPh) { lo = qa + 512; hi = 1024; }
    else      { lo = 0;        hi = qa - 511; }
    float s = 0.f;
    const unsigned short* srow = pbuf + qi * RPW;
    const int kb0 = lo & ~7;
    for (int k8 = kb0 + tq * 8; k8 < hi; k8 += 128) {
      s16x8 v8 = *(const s16x8*)&srow[k8];
#pragma unroll
      for (int e = 0; e < 8; ++e) {
        int k = k8 + e;
        s += (k >= lo && k < hi) ? bf2f((unsigned short)v8[e]) : 0.f;
      }
    }
#pragma unroll
    for (int off = 1; off < 16; off <<= 1) s += __shfl_xor(s, off, 64);
    if (tq == 0) { plS[qi] = isPh ? 0.f : s; phS[qi] = isPh ? s : 0.f; }
  }

  // ---- funnel-shear staging helper state ----
  const int sqi = tid >> 4, stq = tid & 15;
  const int ssh = sqi & 7, shs = ssh >> 1;
  const bool sodd = (ssh & 1) != 0;
  unsigned short* drow = TbPw + sqi * PWP;
  const unsigned short* srowp = pbuf + sqi * RPW;

#define STAGE_PW(base, doSlot0) do {                                         \
    for (int t = stq; t < 64; t += 16) {                                     \
      const int kw0 = (base) + t * 8;                                        \
      s16x8 o;                                                               \
      if (kw0 >= 0 && kw0 + 8 <= 1024) {                                     \
        const int A = kw0 - ssh;                                             \
        union { s16x8 v; unsigned int u[4]; } a0u, a1u, ov;                  \
        a0u.v = *(const s16x8*)&srowp[A];                                    \
        a1u.v = *(const s16x8*)&srowp[A + 8];                                \
        unsigned int wd[8];                                                  \
        _Pragma("unroll")                                                    \
        for (int j2 = 0; j2 < 4; ++j2) { wd[j2] = a0u.u[j2]; wd[4 + j2] = a1u.u[j2]; } \
        unsigned int v7[7];                                                  \
        _Pragma("unroll")                                                    \
        for (int j2 = 0; j2 < 7; ++j2) {                                     \
          unsigned int sf = (wd[j2] >> 16) | (wd[j2 + 1] << 16);             \
          v7[j2] = sodd ? sf : wd[j2];                                       \
        }                                                                    \
        _Pragma("unroll")                                                    \
        for (int j2 = 0; j2 < 4; ++j2) {                                     \
          unsigned int t0 = (shs & 1) ? v7[j2 + 1] : v7[j2];                 \
          unsigned int t1 = (shs & 1) ? v7[j2 + 3] : v7[j2 + 2];             \
          ov.u[j2] = (shs & 2) ? t1 : t0;                                    \
        }                                                                    \
        o = ov.v;                                                            \
      } else if (kw0 + 8 <= 0 || kw0 >= 1024) {                              \
        o = (s16x8){0, 0, 0, 0, 0, 0, 0, 0};                                 \
      } else {                                                               \
        _Pragma("unroll")                                                    \
        for (int e = 0; e < 8; ++e) {                                        \
          int k = kw0 + e;                                                   \
          int kc2 = k < 0 ? 0 : (k > 1023 ? 1023 : k);                       \
          unsigned short vv = srowp[kc2];                                    \
          o[e] = (k >= 0 && k < 1024) ? (short)vv : (short)0;                \
        }                                                                    \
      }                                                                      \
      *(s16x8*)&drow[t * 8] = o;                                             \
      if ((doSlot0) && t == 0) drow[0] = f2bf(plS[sqi]);                     \
    }                                                                        \
  } while (0)

  // stage ph0 window now (same wave as clip wrote plS -> visible without barrier)
  STAGE_PW(q0 + sqi - 512, true);

  // ---- PV: wave w -> d-group w, full k (p from LDS, V^T from global/L2) ----
  f32x4 acc = {0.f, 0.f, 0.f, 0.f};
  const int d0w = w << 4;
  const unsigned short* vrow = Vth + (size_t)(d0w + l15) * 1024 + lhi * 8;
#pragma unroll 8
  for (int kc = 0; kc < 1024; kc += 32) {
    s16x8 pa = *(const s16x8*)&pbuf[l15 * RPW + kc + lhi * 8];
    s16x8 vf = *(const s16x8*)(vrow + kc);
    acc = MFMA16(pa, vf, acc, 0, 0, 0);
  }

  __syncthreads();   // B2: izS, plS/phS, staged-ph0 visible block-wide

  // ---- normalized attn -> d_out (f32, contiguous NT stores) ----
  {
    float* ao = attn_out + ((size_t)bh << 20) + ((size_t)q0 << 10);
#pragma unroll
    for (int n = 0; n < 8; ++n) {
      int row = (tid >> 7) + n * 2;
      int c8 = (tid & 127) << 3;
      float iz = izS[row];
      s16x8 p8 = *(const s16x8*)&pbuf[row * RPW + c8];
      f32x4 o0, o1;
      o0[0] = bf2f((unsigned short)p8[0]) * iz; o0[1] = bf2f((unsigned short)p8[1]) * iz;
      o0[2] = bf2f((unsigned short)p8[2]) * iz; o0[3] = bf2f((unsigned short)p8[3]) * iz;
      o1[0] = bf2f((unsigned short)p8[4]) * iz; o1[1] = bf2f((unsigned short)p8[5]) * iz;
      o1[2] = bf2f((unsigned short)p8[6]) * iz; o1[3] = bf2f((unsigned short)p8[7]) * iz;
      __builtin_nontemporal_store(o0, (f32x4*)(ao + (row << 10) + c8));
      __builtin_nontemporal_store(o1, (f32x4*)(ao + (row << 10) + c8 + 4));
    }
  }

  // ---- rel_v GEMM phase 0 (reads staged TbPw) ----
  const unsigned short* rrow = rvT + (size_t)(d0w + l15) * 1040 + lhi * 8;
#pragma unroll 8
  for (int kc = 0; kc < 512; kc += 32) {
    s16x8 pa = *(const s16x8*)&TbPw[l15 * PWP + kc + lhi * 8];
    s16x8 rb = *(const s16x8*)(rrow + kc);
    acc = MFMA16(pa, rb, acc, 0, 0, 0);
  }

  __syncthreads();   // B3: ph0 reads done
  STAGE_PW(q0 + sqi, false);
  __syncthreads();   // B4: ph1 staged

#pragma unroll 8
  for (int kc = 0; kc < 512; kc += 32) {
    s16x8 pa = *(const s16x8*)&TbPw[l15 * PWP + kc + lhi * 8];
    s16x8 rb = *(const s16x8*)(rrow + 512 + kc);
    acc = MFMA16(pa, rb, acc, 0, 0, 0);
  }
#undef STAGE_PW

  // ---- epilogue: + phigh * rel_v[1024], scale by iz, scrambled bf16 store ----
  float rv1024 = bf2f(rvT[(size_t)(d0w + l15) * 1040 + 1024]);
  const size_t fb = ((size_t)(bh >> 2) << 18) + ((size_t)(bh & 3) << 6);
#pragma unroll
  for (int j = 0; j < 4; ++j) {
    int qi = lhi * 4 + j;
    float v = (acc[j] + phS[qi] * rv1024) * izS[qi];
    xscr[fb + ((size_t)(q0 + qi) << 8) + d0w + l15] = f2bf(v);
  }
}

extern "C" void kernel_launch(void* const* d_in, const int* in_sizes, int n_in,
                              void* d_out, int out_size, void* d_ws, size_t ws_size,
                              hipStream_t stream) {
  (void)in_sizes; (void)n_in; (void)out_size; (void)ws_size;
  const float* query = (const float*)d_in[0];
  const float* key   = (const float*)d_in[1];
  const float* value = (const float*)d_in[2];
  const float* Wq = (const float*)d_in[3];
  const float* bq = (const float*)d_in[4];
  const float* Wk = (const float*)d_in[5];
  const float* bk = (const float*)d_in[6];
  const float* Wv = (const float*)d_in[7];
  const float* bv = (const float*)d_in[8];
  const float* Wo = (const float*)d_in[9];
  const float* bo = (const float*)d_in[10];
  const float* rel_k = (const float*)d_in[11];
  const float* rel_v = (const float*)d_in[12];

  char* ws = (char*)d_ws;
  const size_t MB = 1024 * 1024;
  unsigned short* qb    = (unsigned short*)(ws);            //  0-8 MB
  unsigned short* kbuf  = (unsigned short*)(ws + 8 * MB);   //  8-16
  unsigned short* xscr  = (unsigned short*)(ws + 16 * MB);  // 16-24 (scratch for attn X)
  unsigned short* vTb   = (unsigned short*)(ws + 24 * MB);  // 24-32 (V written transposed by QKV GEMM)
  unsigned short* wqt   = (unsigned short*)(ws + 32 * MB);  // 32-34
  unsigned short* wkt   = (unsigned short*)(ws + 34 * MB);  // 34-36
  unsigned short* wvt   = (unsigned short*)(ws + 36 * MB);  // 36-38
  unsigned short* wot   = (unsigned short*)(ws + 38 * MB);  // 38-40
  unsigned short* relkb = (unsigned short*)(ws + 40 * MB);              // ~0.13 MB
  unsigned short* rvTb  = (unsigned short*)(ws + 40 * MB + 256 * 1024); // ~0.13 MB

  float* out0 = (float*)d_out;
  float* attn_out = out0 + 4194304;

  k_prep<<<4386, 256, 0, stream>>>(Wq, Wk, Wv, Wo, wqt, wkt, wvt, wot,
                                   rel_k, rel_v, relkb, rvTb);

  // Q/K per-head layout; V written directly transposed -> k_trV eliminated
  k_gemm_qkv<<<dim3(16, 32, 3), 256, 0, stream>>>(query, key, value,
                                                  wqt, wkt, wvt,
                                                  bq, bk, bv,
                                                  qb, kbuf, vTb);

  k_attn<<<4096, 256, 0, stream>>>(qb, kbuf, vTb, relkb, rvTb, attn_out, xscr);

  k_gemm_o<<<dim3(16, 32), 256, 0, stream>>>(xscr, wot, bo, out0);
}